// Round 4
// baseline (263.036 us; speedup 1.0000x reference)
//
#include <hip/hip_runtime.h>
#include <math.h>

// Fixed problem shape: B=8, N=M=4096, 3-D f32 points.
#define NPTS  4096
#define NB    8
#define TPB   1024
#define QB    256            // queries per block
#define HALF  2048           // candidates per block (half the cloud)
#define SEGS  16             // one wave per segment
#define CPS   (HALF / SEGS)  // 128 candidates per segment
#define GRID  512            // 2 dirs * 8 batches * 16 qblks * 2 halves
#define NQTOT 65536          // 2 * 8 * 4096 queries

// ws layout: u64 gmin[65536] (poison 0xAA.. acts as +inf for packed
// (distbits<<32)|idx minima), then u32 counter (poison 0xAAAAAAAA known).
__global__ __launch_bounds__(TPB, 8) void chamfer4_kernel(
    const float* __restrict__ xyz1, const float* __restrict__ xyz2,
    const float* __restrict__ nrm1, const float* __restrict__ nrm2,
    unsigned long long* __restrict__ gmin, unsigned int* __restrict__ cnt,
    float* __restrict__ out)
{
    __shared__ float4 sc[HALF];          // 32 KB candidate stage (x,y,z,r^2)
    __shared__ float  sBest[SEGS * QB];  // 16 KB per-segment per-query minima
    __shared__ float  qMin[QB];
    __shared__ int    qSeg[QB];
    __shared__ float4 qM[QB];            // (-2qx,-2qy,-2qz, |q|^2)
    __shared__ float  fin[32];
    __shared__ int    sLast;

    int bid  = blockIdx.x;
    int dir  = bid >> 8;
    int b    = (bid >> 5) & 7;
    int qblk = (bid >> 1) & 15;
    int half = bid & 1;

    int tid  = threadIdx.x;
    int lane = tid & 63;
    int wid  = tid >> 6;

    const float* qb = (dir ? xyz2 : xyz1) + (size_t)b * NPTS * 3;
    const float* rb = (dir ? xyz1 : xyz2) + ((size_t)b * NPTS + half * HALF) * 3;

    // ---- stage 2048 candidates as (x,y,z,r^2) ----
    if (tid < 512) {
        const float4* rb4 = (const float4*)rb;   // 24 KB, 16B-aligned
        float4 v0 = rb4[tid * 3 + 0];
        float4 v1 = rb4[tid * 3 + 1];
        float4 v2 = rb4[tid * 3 + 2];
        int p = tid * 4;
        sc[p + 0] = make_float4(v0.x, v0.y, v0.z, fmaf(v0.x, v0.x, fmaf(v0.y, v0.y, v0.z * v0.z)));
        sc[p + 1] = make_float4(v0.w, v1.x, v1.y, fmaf(v0.w, v0.w, fmaf(v1.x, v1.x, v1.y * v1.y)));
        sc[p + 2] = make_float4(v1.z, v1.w, v2.x, fmaf(v1.z, v1.z, fmaf(v1.w, v1.w, v2.x * v2.x)));
        sc[p + 3] = make_float4(v2.y, v2.z, v2.w, fmaf(v2.y, v2.y, fmaf(v2.z, v2.z, v2.w * v2.w)));
    }
    __syncthreads();

    // ---- value-only scan: 4 queries/thread, 2 min3 chains each ----
    float mx[4], my[4], mz[4];
    #pragma unroll
    for (int u = 0; u < 4; ++u) {
        const float* p = qb + (qblk * QB + u * 64 + lane) * 3;
        mx[u] = -2.f * p[0]; my[u] = -2.f * p[1]; mz[u] = -2.f * p[2];
    }
    float bE[4], bO[4];
    #pragma unroll
    for (int u = 0; u < 4; ++u) { bE[u] = INFINITY; bO[u] = INFINITY; }

    int jb = wid * CPS;
    #pragma unroll 8
    for (int jo = 0; jo < CPS; jo += 4) {
        float4 c0 = sc[jb + jo + 0];   // broadcast reads (wave-uniform addr)
        float4 c1 = sc[jb + jo + 1];
        float4 c2 = sc[jb + jo + 2];
        float4 c3 = sc[jb + jo + 3];
        #pragma unroll
        for (int u = 0; u < 4; ++u) {
            float d0 = fmaf(mx[u], c0.x, fmaf(my[u], c0.y, fmaf(mz[u], c0.z, c0.w)));
            float d1 = fmaf(mx[u], c1.x, fmaf(my[u], c1.y, fmaf(mz[u], c1.z, c1.w)));
            float d2 = fmaf(mx[u], c2.x, fmaf(my[u], c2.y, fmaf(mz[u], c2.z, c2.w)));
            float d3 = fmaf(mx[u], c3.x, fmaf(my[u], c3.y, fmaf(mz[u], c3.z, c3.w)));
            bE[u] = fminf(fminf(bE[u], d0), d2);   // -> v_min3_f32
            bO[u] = fminf(fminf(bO[u], d1), d3);
        }
    }
    #pragma unroll
    for (int u = 0; u < 4; ++u)
        sBest[wid * QB + u * 64 + lane] = fminf(bE[u], bO[u]);
    __syncthreads();

    // ---- combine across segments (value + first winning segment) ----
    if (tid < QB) {
        float best = sBest[tid]; int bs = 0;
        #pragma unroll
        for (int s = 1; s < SEGS; ++s) {
            float v = sBest[s * QB + tid];
            if (v < best) { best = v; bs = s; }   // strict <: lowest seg on tie
        }
        qMin[tid] = best; qSeg[tid] = bs;
        const float* p = qb + (qblk * QB + tid) * 3;
        float qx = p[0], qy = p[1], qz = p[2];
        qM[tid] = make_float4(-2.f * qx, -2.f * qy, -2.f * qz,
                              fmaf(qx, qx, fmaf(qy, qy, qz * qz)));
    }
    __syncthreads();

    // ---- rescan winning segment to recover first argmin; pack+atomicMin ----
    unsigned int qglob0 = (unsigned)(dir * (NB * NPTS) + b * NPTS + qblk * QB);
    #pragma unroll 4
    for (int k = 0; k < 16; ++k) {
        int q = wid * 16 + k;
        float minv = qMin[q];
        int   seg  = qSeg[q];
        float4 m   = qM[q];
        float4 ca  = sc[seg * CPS + lane];
        float4 cb  = sc[seg * CPS + 64 + lane];
        float da = fmaf(m.x, ca.x, fmaf(m.y, ca.y, fmaf(m.z, ca.z, ca.w)));
        float db = fmaf(m.x, cb.x, fmaf(m.y, cb.y, fmaf(m.z, cb.z, cb.w)));
        unsigned long long ba = __ballot(da == minv);   // exact FMA replay
        unsigned long long bb = __ballot(db == minv);
        if (lane == 0) {
            int off = ba ? (__ffsll(ba) - 1) : (64 + __ffsll(bb) - 1);
            int gidx = half * HALF + seg * CPS + off;      // 0..4095
            float dist = fmaxf(minv + m.w, 0.f);           // |q|^2 + min(r^2-2qr)
            unsigned long long pk =
                ((unsigned long long)__float_as_uint(dist) << 32) | (unsigned)gidx;
            atomicMin(&gmin[qglob0 + q], pk);   // poison 0xAA.. > any pk
        }
    }

    // ---- last-block-done: finalize normals + means in one kernel ----
    __threadfence();
    __syncthreads();
    if (tid == 0) {
        unsigned int old = atomicAdd(cnt, 1u);             // cnt poison known
        sLast = (old == 0xAAAAAAAAu + (GRID - 1)) ? 1 : 0;
    }
    __syncthreads();
    if (!sLast) return;
    __threadfence();

    float sd = 0.f, sn = 0.f;
    #pragma unroll 4
    for (int i = 0; i < NQTOT / TPB; ++i) {
        int gq  = i * TPB + tid;
        int d2  = gq >> 15;            // direction
        int rem = gq & 32767;          // b*4096 + n
        int bb  = rem >> 12;           // batch
        unsigned long long pk = gmin[gq];
        float dist = __uint_as_float((unsigned)(pk >> 32));
        int   idx  = (int)(pk & 0xFFFFFFFFu);              // 0..4095
        const float* a3 = (d2 ? nrm2 : nrm1) + (size_t)rem * 3;
        const float* t3 = (d2 ? nrm1 : nrm2) + ((size_t)bb * NPTS + idx) * 3;
        float ax = a3[0], ay = a3[1], az = a3[2];
        float ia = 1.f / fmaxf(sqrtf(fmaf(ax, ax, fmaf(ay, ay, az * az))), 1e-12f);
        ax *= ia; ay *= ia; az *= ia;
        float bx = t3[0], by = t3[1], bz = t3[2];
        float ib = 1.f / fmaxf(sqrtf(fmaf(bx, bx, fmaf(by, by, bz * bz))), 1e-12f);
        bx *= ib; by *= ib; bz *= ib;
        float ex = ax - bx, ey = ay - by, ez = az - bz;
        float px = ax + bx, py = ay + by, pz = az + bz;
        float dm = fmaf(ex, ex, fmaf(ey, ey, ez * ez));
        float dp = fmaf(px, px, fmaf(py, py, pz * pz));
        sd += dist;
        sn += fminf(dm, dp);
    }
    for (int off = 32; off > 0; off >>= 1) {
        sd += __shfl_down(sd, off, 64);
        sn += __shfl_down(sn, off, 64);
    }
    if (lane == 0) { fin[wid * 2 + 0] = sd; fin[wid * 2 + 1] = sn; }
    __syncthreads();
    if (tid == 0) {
        float a = 0.f, c = 0.f;
        #pragma unroll
        for (int w = 0; w < 16; ++w) { a += fin[w * 2]; c += fin[w * 2 + 1]; }
        const float inv = 1.0f / 32768.0f;
        out[0] = a * inv;   // loss_xyz   = (sum dist1 + sum dist2)/32768
        out[1] = c * inv;   // loss_normal (same count both dirs)
    }
}

extern "C" void kernel_launch(void* const* d_in, const int* in_sizes, int n_in,
                              void* d_out, int out_size, void* d_ws, size_t ws_size,
                              hipStream_t stream) {
    const float* xyz1 = (const float*)d_in[0];   // [8,4096,3]
    const float* xyz2 = (const float*)d_in[1];
    const float* nrm1 = (const float*)d_in[2];   // normal_rebuild
    const float* nrm2 = (const float*)d_in[3];   // normal_gt
    float* out = (float*)d_out;

    unsigned long long* gmin = (unsigned long long*)d_ws;        // 512 KB
    unsigned int* cnt = (unsigned int*)((char*)d_ws + (size_t)NQTOT * 8);

    // Single dispatch: poison 0xAA.. in ws serves as +inf for gmin and as the
    // known start value for cnt; harness re-poisons ws before every launch.
    chamfer4_kernel<<<GRID, TPB, 0, stream>>>(xyz1, xyz2, nrm1, nrm2, gmin, cnt, out);
}

// Round 5
// 88.365 us; speedup vs baseline: 2.9767x; 2.9767x over previous
//
#include <hip/hip_runtime.h>
#include <math.h>

// Fixed problem shape: B=8, N=M=4096, 3-D f32 points.
#define NPTS  4096
#define NB    8
#define TPB   1024
#define QB    256            // queries per block
#define HALF  2048           // candidates per block (half the cloud)
#define SEGS  16             // one wave per segment
#define CPS   (HALF / SEGS)  // 128 candidates per segment
#define GRID1 512            // 2 dirs * 8 batches * 16 qblks * 2 halves
#define NQTOT 65536          // 2 * 8 * 4096 queries

// ws layout: u64 res[2][65536]  (per-half packed (distbits<<32)|idx, plain
// coalesced stores, no atomics), then f32 part[128] (64 blocks x 2 partials).

// Kernel 1: value-only min3 scan + exact argmin recovery via segment rescan.
__global__ __launch_bounds__(TPB, 8) void chamfer5_kernel(
    const float* __restrict__ xyz1, const float* __restrict__ xyz2,
    unsigned long long* __restrict__ res)
{
    __shared__ float4 sc[HALF];                    // 32 KB (x,y,z,|r|^2)
    __shared__ float  sBest[SEGS * QB];            // 16 KB
    __shared__ float  qMin[QB];
    __shared__ int    qSeg[QB];
    __shared__ float4 qM[QB];                      // (-2qx,-2qy,-2qz,|q|^2)
    __shared__ unsigned long long qPk[QB];         // 2 KB packed results

    int bid  = blockIdx.x;
    int dir  = bid >> 8;
    int b    = (bid >> 5) & 7;
    int qblk = (bid >> 1) & 15;
    int half = bid & 1;

    int tid  = threadIdx.x;
    int lane = tid & 63;
    int wid  = tid >> 6;

    const float* qb = (dir ? xyz2 : xyz1) + (size_t)b * NPTS * 3;
    const float* rb = (dir ? xyz1 : xyz2) + ((size_t)b * NPTS + half * HALF) * 3;

    // ---- stage 2048 candidates as (x,y,z,r^2) ----
    if (tid < 512) {
        const float4* rb4 = (const float4*)rb;     // 24 KB, 16B-aligned
        float4 v0 = rb4[tid * 3 + 0];
        float4 v1 = rb4[tid * 3 + 1];
        float4 v2 = rb4[tid * 3 + 2];
        int p = tid * 4;
        sc[p + 0] = make_float4(v0.x, v0.y, v0.z, fmaf(v0.x, v0.x, fmaf(v0.y, v0.y, v0.z * v0.z)));
        sc[p + 1] = make_float4(v0.w, v1.x, v1.y, fmaf(v0.w, v0.w, fmaf(v1.x, v1.x, v1.y * v1.y)));
        sc[p + 2] = make_float4(v1.z, v1.w, v2.x, fmaf(v1.z, v1.z, fmaf(v1.w, v1.w, v2.x * v2.x)));
        sc[p + 3] = make_float4(v2.y, v2.z, v2.w, fmaf(v2.y, v2.y, fmaf(v2.z, v2.z, v2.w * v2.w)));
    }
    __syncthreads();

    // ---- value-only scan: 4 queries/thread, 2 min3 chains each ----
    float mx[4], my[4], mz[4];
    #pragma unroll
    for (int u = 0; u < 4; ++u) {
        const float* p = qb + (qblk * QB + u * 64 + lane) * 3;
        mx[u] = -2.f * p[0]; my[u] = -2.f * p[1]; mz[u] = -2.f * p[2];
    }
    float bE[4], bO[4];
    #pragma unroll
    for (int u = 0; u < 4; ++u) { bE[u] = INFINITY; bO[u] = INFINITY; }

    int jb = wid * CPS;
    #pragma unroll 2
    for (int jo = 0; jo < CPS; jo += 4) {
        float4 c0 = sc[jb + jo + 0];   // broadcast reads (wave-uniform addr)
        float4 c1 = sc[jb + jo + 1];
        float4 c2 = sc[jb + jo + 2];
        float4 c3 = sc[jb + jo + 3];
        #pragma unroll
        for (int u = 0; u < 4; ++u) {
            float d0 = fmaf(mx[u], c0.x, fmaf(my[u], c0.y, fmaf(mz[u], c0.z, c0.w)));
            float d1 = fmaf(mx[u], c1.x, fmaf(my[u], c1.y, fmaf(mz[u], c1.z, c1.w)));
            float d2 = fmaf(mx[u], c2.x, fmaf(my[u], c2.y, fmaf(mz[u], c2.z, c2.w)));
            float d3 = fmaf(mx[u], c3.x, fmaf(my[u], c3.y, fmaf(mz[u], c3.z, c3.w)));
            bE[u] = fminf(fminf(bE[u], d0), d2);   // -> v_min3_f32
            bO[u] = fminf(fminf(bO[u], d1), d3);
        }
    }
    #pragma unroll
    for (int u = 0; u < 4; ++u)
        sBest[wid * QB + u * 64 + lane] = fminf(bE[u], bO[u]);
    __syncthreads();

    // ---- combine across segments (value + first winning segment) ----
    if (tid < QB) {
        float best = sBest[tid]; int bs = 0;
        #pragma unroll
        for (int s = 1; s < SEGS; ++s) {
            float v = sBest[s * QB + tid];
            if (v < best) { best = v; bs = s; }   // strict <: lowest seg on tie
        }
        qMin[tid] = best; qSeg[tid] = bs;
        const float* p = qb + (qblk * QB + tid) * 3;
        float qx = p[0], qy = p[1], qz = p[2];
        qM[tid] = make_float4(-2.f * qx, -2.f * qy, -2.f * qz,
                              fmaf(qx, qx, fmaf(qy, qy, qz * qz)));
    }
    __syncthreads();

    // ---- rescan winning segment: exact FMA replay + ballot-ffs argmin ----
    #pragma unroll 4
    for (int k = 0; k < 16; ++k) {
        int q = wid * 16 + k;
        float minv = qMin[q];
        int   seg  = qSeg[q];
        float4 m   = qM[q];
        float4 ca  = sc[seg * CPS + lane];
        float4 cb  = sc[seg * CPS + 64 + lane];
        float da = fmaf(m.x, ca.x, fmaf(m.y, ca.y, fmaf(m.z, ca.z, ca.w)));
        float db = fmaf(m.x, cb.x, fmaf(m.y, cb.y, fmaf(m.z, cb.z, cb.w)));
        unsigned long long ba = __ballot(da == minv);
        unsigned long long bb = __ballot(db == minv);
        if (lane == 0) {
            int off = ba ? (__ffsll(ba) - 1) : (64 + __ffsll(bb) - 1);
            int gidx = half * HALF + seg * CPS + off;     // 0..4095
            float dist = fmaxf(minv + m.w, 0.f);          // |q|^2 + min(r^2-2qr)
            qPk[q] = ((unsigned long long)__float_as_uint(dist) << 32)
                     | (unsigned)gidx;
        }
    }
    __syncthreads();

    // ---- coalesced store of 256 packed results ----
    if (tid < QB) {
        unsigned qglob = (unsigned)(dir * (NB * NPTS) + b * NPTS + qblk * QB + tid);
        res[(size_t)half * NQTOT + qglob] = qPk[tid];
    }
}

// Kernel 2: combine halves (u64 min == first-min on (dist,idx)), normal term,
// per-block partial sums. 64 blocks x 1024 threads = 65536 queries.
__global__ __launch_bounds__(TPB) void chamfer5_finalize(
    const float* __restrict__ nrm1, const float* __restrict__ nrm2,
    const unsigned long long* __restrict__ res, float* __restrict__ part)
{
    __shared__ float fin[32];
    int tid = threadIdx.x;
    int gq  = blockIdx.x * TPB + tid;

    unsigned long long pk0 = res[gq];
    unsigned long long pk1 = res[NQTOT + gq];
    unsigned long long pk  = pk0 < pk1 ? pk0 : pk1;
    float dist = __uint_as_float((unsigned)(pk >> 32));
    int   idx  = (int)(pk & 0xFFFFFFFFu);          // 0..4095

    int d2  = gq >> 15;            // direction
    int rem = gq & 32767;          // b*4096 + n
    int bb  = rem >> 12;           // batch

    const float* a3 = (d2 ? nrm2 : nrm1) + (size_t)rem * 3;
    const float* t3 = (d2 ? nrm1 : nrm2) + ((size_t)bb * NPTS + idx) * 3;
    float ax = a3[0], ay = a3[1], az = a3[2];
    float ia = 1.f / fmaxf(sqrtf(fmaf(ax, ax, fmaf(ay, ay, az * az))), 1e-12f);
    ax *= ia; ay *= ia; az *= ia;
    float bx = t3[0], by = t3[1], bz = t3[2];
    float ib = 1.f / fmaxf(sqrtf(fmaf(bx, bx, fmaf(by, by, bz * bz))), 1e-12f);
    bx *= ib; by *= ib; bz *= ib;
    float ex = ax - bx, ey = ay - by, ez = az - bz;
    float px = ax + bx, py = ay + by, pz = az + bz;
    float dm = fmaf(ex, ex, fmaf(ey, ey, ez * ez));
    float dp = fmaf(px, px, fmaf(py, py, pz * pz));
    float nd = fminf(dm, dp);

    for (int off = 32; off > 0; off >>= 1) {
        dist += __shfl_down(dist, off, 64);
        nd   += __shfl_down(nd,   off, 64);
    }
    int wave = tid >> 6, lane = tid & 63;
    if (lane == 0) { fin[wave * 2] = dist; fin[wave * 2 + 1] = nd; }
    __syncthreads();
    if (tid == 0) {
        float a = 0.f, c = 0.f;
        #pragma unroll
        for (int w = 0; w < 16; ++w) { a += fin[w * 2]; c += fin[w * 2 + 1]; }
        part[blockIdx.x * 2 + 0] = a;
        part[blockIdx.x * 2 + 1] = c;
    }
}

// Kernel 3: reduce 64x2 partials -> 2 outputs (means; N==M so both dirs
// share the 1/32768 factor).
__global__ __launch_bounds__(64) void chamfer5_reduce(
    const float* __restrict__ part, float* __restrict__ out)
{
    int t = threadIdx.x;                 // 0..63
    float sd = part[t * 2 + 0];
    float sn = part[t * 2 + 1];
    for (int off = 32; off > 0; off >>= 1) {
        sd += __shfl_down(sd, off, 64);
        sn += __shfl_down(sn, off, 64);
    }
    if (t == 0) {
        const float inv = 1.0f / 32768.0f;
        out[0] = sd * inv;   // loss_xyz
        out[1] = sn * inv;   // loss_normal
    }
}

extern "C" void kernel_launch(void* const* d_in, const int* in_sizes, int n_in,
                              void* d_out, int out_size, void* d_ws, size_t ws_size,
                              hipStream_t stream) {
    const float* xyz1 = (const float*)d_in[0];   // [8,4096,3]
    const float* xyz2 = (const float*)d_in[1];
    const float* nrm1 = (const float*)d_in[2];   // normal_rebuild
    const float* nrm2 = (const float*)d_in[3];   // normal_gt
    float* out = (float*)d_out;

    unsigned long long* res = (unsigned long long*)d_ws;          // 1 MB
    float* part = (float*)((char*)d_ws + (size_t)2 * NQTOT * 8);  // 512 B

    chamfer5_kernel<<<GRID1, TPB, 0, stream>>>(xyz1, xyz2, res);
    chamfer5_finalize<<<NQTOT / TPB, TPB, 0, stream>>>(nrm1, nrm2, res, part);
    chamfer5_reduce<<<1, 64, 0, stream>>>(part, out);
}